// Round 10
// baseline (380.128 us; speedup 1.0000x reference)
//
#include <hip/hip_runtime.h>
#include <hip/hip_fp16.h>

#define HF 32
#define EPS 1e-5f
#define BSH 8
#define BSZ 256          // nodes per bucket
#define CH  4096         // edges per binning block
#define SUBCAP 1024      // per-XCD sub-segment capacity
#define CAP (8*SUBCAP)   // bucket segment capacity

typedef int   vi4 __attribute__((ext_vector_type(4)));
typedef float vf4 __attribute__((ext_vector_type(4)));

__device__ __forceinline__ float leaky(float v){ return fmaxf(v, 0.01f*v); }
__device__ __forceinline__ float elu1(float v){ return v > 0.f ? v : (expf(v)-1.f); }
__device__ __forceinline__ float sigmoidf(float v){ return 1.f/(1.f+expf(-v)); }

// nt 16B index load -> int4
__device__ __forceinline__ int4 nt_load_i4(const int* p){
    vi4 v = __builtin_nontemporal_load((const vi4*)p);
    return make_int4(v.x, v.y, v.z, v.w);
}
// nt 16B store of packed halves
__device__ __forceinline__ void nt_store_f4(float4 v, float4* p){
    vf4 t; t.x = v.x; t.y = v.y; t.z = v.z; t.w = v.w;
    __builtin_nontemporal_store(t, (vf4*)p);
}

// add 8 halfs (16B) into fp32 accumulator
__device__ __forceinline__ void addrow8(float* a, float4 v){
    const __half2* p = (const __half2*)&v;
#pragma unroll
    for (int k = 0; k < 4; k++){
        float2 f = __half22float2(p[k]);
        a[2*k] += f.x; a[2*k+1] += f.y;
    }
}
// packed fp16 add of two 8-half rows
__device__ __forceinline__ float4 h2add4f(float4 a, float4 b){
    __half2* pa = (__half2*)&a; __half2* pb = (__half2*)&b;
    float4 r; __half2* pr = (__half2*)&r;
#pragma unroll
    for (int k = 0; k < 4; k++) pr[k] = __hadd2(pa[k], pb[k]);
    return r;
}

// ===== fused: input MLP + BN stats  |  edge binning (block-range split) =====
union SMem {
    struct {
        float sW1[3*HF]; float sB1[HF]; float sW2[HF*HF]; float sB2[HF];
        float sh[256][33];
    } mlp;
    struct { int lcnt[512]; int lbase[512]; int lpos[512]; } bin;
};

__global__ __launch_bounds__(256)
void k_mlp_bin(const float* __restrict__ x,
               const float* __restrict__ w1, const float* __restrict__ b1,
               const float* __restrict__ w2, const float* __restrict__ b2,
               __half* __restrict__ h, float* __restrict__ stats,
               const int* __restrict__ src, const int* __restrict__ dst,
               int* __restrict__ gfill, int* __restrict__ ep,
               int N, int E, int B, int NB1){
    __shared__ SMem sm;
    int t = threadIdx.x;
    if ((int)blockIdx.x < NB1){
        // ---------------- MLP + stats ----------------
        for (int i = t; i < 3*HF; i += 256) sm.mlp.sW1[i] = w1[i];
        if (t < HF){ sm.mlp.sB1[t] = b1[t]; sm.mlp.sB2[t] = b2[t]; }
        for (int i = t; i < HF*HF; i += 256) sm.mlp.sW2[i] = w2[i];
        __syncthreads();
        int n = blockIdx.x*256 + t;
        float h2[HF];
        if (n < N){
            float x0 = x[(size_t)n*3], x1 = x[(size_t)n*3+1], x2 = x[(size_t)n*3+2];
            float h1[HF];
#pragma unroll
            for (int j = 0; j < HF; j++){
                float v = fmaf(x0, sm.mlp.sW1[j], fmaf(x1, sm.mlp.sW1[HF+j],
                          fmaf(x2, sm.mlp.sW1[2*HF+j], sm.mlp.sB1[j])));
                h1[j] = leaky(v);
            }
#pragma unroll
            for (int j = 0; j < HF; j++){
                float v = sm.mlp.sB2[j];
#pragma unroll
                for (int i = 0; i < HF; i++) v = fmaf(h1[i], sm.mlp.sW2[i*HF+j], v);
                h2[j] = leaky(v);
            }
            float4* hv = (float4*)(h + (size_t)n*HF);
#pragma unroll
            for (int jb = 0; jb < 4; jb++){
                __half2 hh[4];
#pragma unroll
                for (int k = 0; k < 4; k++)
                    hh[k] = __float22half2_rn(make_float2(h2[jb*8+2*k], h2[jb*8+2*k+1]));
                hv[jb] = *(float4*)hh;
            }
        } else {
#pragma unroll
            for (int j = 0; j < HF; j++) h2[j] = 0.f;
        }
#pragma unroll
        for (int j = 0; j < HF; j++) sm.mlp.sh[t][j] = h2[j];
        __syncthreads();
        int f = t & 31, g = t >> 5;
        float s = 0.f, ss = 0.f;
        for (int i = 0; i < 32; i++){
            float v = sm.mlp.sh[g*32 + i][f];
            s += v; ss += v*v;
        }
        __syncthreads();
        sm.mlp.sh[g][f] = s; sm.mlp.sh[8+g][f] = ss;
        __syncthreads();
        if (t < HF){
            float a = 0.f, b = 0.f;
#pragma unroll
            for (int g2 = 0; g2 < 8; g2++){ a += sm.mlp.sh[g2][t]; b += sm.mlp.sh[8+g2][t]; }
            atomicAdd(&stats[t], a);
            atomicAdd(&stats[HF+t], b);
        }
    } else {
        // ---------------- binning ----------------
        int bid = blockIdx.x - NB1;
        for (int i = t; i < B; i += 256){ sm.bin.lcnt[i] = 0; sm.bin.lpos[i] = 0; }
        __syncthreads();
        int base = bid * CH;
        int xcd = blockIdx.x & 7;
        int dv[16], sv[16];
#pragma unroll
        for (int i = 0; i < 16; i++){
            int e = base + t + i*256;
            dv[i] = (e < E) ? __builtin_nontemporal_load(&dst[e]) : -1;
            sv[i] = (e < E) ? __builtin_nontemporal_load(&src[e]) : 0;
        }
#pragma unroll
        for (int i = 0; i < 16; i++)
            if (dv[i] >= 0) atomicAdd(&sm.bin.lcnt[dv[i] >> BSH], 1);
        __syncthreads();
        for (int i = t; i < B; i += 256){
            int c = sm.bin.lcnt[i];
            sm.bin.lbase[i] = c ? (i*CAP + xcd*SUBCAP + atomicAdd(&gfill[i*8 + xcd], c)) : 0;
        }
        __syncthreads();
#pragma unroll
        for (int i = 0; i < 16; i++){
            if (dv[i] >= 0){
                int d = dv[i], bb = d >> BSH;
                int p = sm.bin.lbase[bb] + atomicAdd(&sm.bin.lpos[bb], 1);
                __builtin_nontemporal_store((sv[i] << BSH) | (d & (BSZ-1)), &ep[p]);
            }
        }
    }
}

// ------- per-bucket CSR build: rowp2, dis; ep rewritten as sorted src -------
__global__ __launch_bounds__(256)
void k_bucketD(int* __restrict__ ep, const int* __restrict__ gfill,
               int2* __restrict__ rowp2, float* __restrict__ dis, int N, int B){
    __shared__ int sep[CAP];
    __shared__ int lcnt[256], lpre[256], lfill[256], sc[256];
    int b = blockIdx.x, t = threadIdx.x;
    int cx[8], coff[8], cnt = 0;
#pragma unroll
    for (int x = 0; x < 8; x++){ cx[x] = gfill[b*8 + x]; coff[x] = cnt; cnt += cx[x]; }
    lcnt[t] = 0; lfill[t] = 0;
    __syncthreads();
    int base = b*CAP;
#pragma unroll
    for (int x = 0; x < 8; x++)
        for (int j = t; j < cx[x]; j += 256)
            sep[coff[x] + j] = __builtin_nontemporal_load(&ep[base + x*SUBCAP + j]);
    __syncthreads();
    for (int e = t; e < cnt; e += 256) atomicAdd(&lcnt[sep[e] & (BSZ-1)], 1);
    __syncthreads();
    int v = lcnt[t];
    sc[t] = v; __syncthreads();
    for (int off = 1; off < 256; off <<= 1){
        int u = (t >= off) ? sc[t - off] : 0;
        __syncthreads();
        sc[t] += u;
        __syncthreads();
    }
    int pre = sc[t] - v;
    lpre[t] = pre;
    int n = b*BSZ + t;
    if (n < N){
        rowp2[n] = make_int2(base + pre, base + pre + v);
        dis[n]   = rsqrtf((float)(v + 1));
    }
    __syncthreads();
    for (int e = t; e < cnt; e += 256){
        int val = sep[e];
        int d = val & (BSZ-1);
        int p = lpre[d] + atomicAdd(&lfill[d], 1);
        __builtin_nontemporal_store(val >> BSH, &ep[base + p]);   // plain src idx
    }
}

// ------- BN + first transform: t1 = ((bn(h))@W)*dis, fp16 row layout --------
__global__ __launch_bounds__(256)
void k_bn_t1(const __half* __restrict__ h, const float* __restrict__ stats,
             const float* __restrict__ gamma, const float* __restrict__ beta,
             const float* __restrict__ W, const float* __restrict__ dis,
             __half* __restrict__ tout, int N){
    __shared__ float sW[HF*HF];
    __shared__ float sh[64][33];
    int tid = threadIdx.x;
    for (int i = tid; i < HF*HF; i += 256) sW[i] = W[i];
    int nib = tid >> 2, l = tid & 3;
    int n = blockIdx.x*64 + nib;
    float hv[8];
    float d = 0.f;
    if (n < N){
        float4 raw = ((const float4*)h)[(size_t)n*4 + l];
        const __half2* p = (const __half2*)&raw;
        float tmp[8];
#pragma unroll
        for (int k = 0; k < 4; k++){
            float2 f2 = __half22float2(p[k]);
            tmp[2*k] = f2.x; tmp[2*k+1] = f2.y;
        }
        d = dis[n];
        float inv = 1.0f / (float)N;
#pragma unroll
        for (int c = 0; c < 8; c++){
            int f = 8*l + c;
            float mu  = stats[f]    * inv;
            float var = stats[HF+f] * inv - mu*mu;
            float rs  = rsqrtf(var + EPS);
            hv[c] = (tmp[c] - mu) * rs * gamma[f] + beta[f];
        }
    } else {
#pragma unroll
        for (int c = 0; c < 8; c++) hv[c] = 0.f;
    }
    __syncthreads();
#pragma unroll
    for (int c = 0; c < 8; c++) sh[nib][8*l + c] = hv[c];
    __syncthreads();
    float o[8] = {0.f,0.f,0.f,0.f,0.f,0.f,0.f,0.f};
#pragma unroll
    for (int i = 0; i < HF; i++){
        float hvv = sh[nib][i];
        float4 w0 = *(const float4*)&sW[i*HF + 8*l];
        float4 w1 = *(const float4*)&sW[i*HF + 8*l + 4];
        o[0] = fmaf(hvv, w0.x, o[0]); o[1] = fmaf(hvv, w0.y, o[1]);
        o[2] = fmaf(hvv, w0.z, o[2]); o[3] = fmaf(hvv, w0.w, o[3]);
        o[4] = fmaf(hvv, w1.x, o[4]); o[5] = fmaf(hvv, w1.y, o[5]);
        o[6] = fmaf(hvv, w1.z, o[6]); o[7] = fmaf(hvv, w1.w, o[7]);
    }
    if (n < N){
        __half2 hh[4];
#pragma unroll
        for (int k = 0; k < 4; k++)
            hh[k] = __float22half2_rn(make_float2(o[2*k]*d, o[2*k+1]*d));
        ((float4*)tout)[(size_t)n*4 + l] = *(float4*)hh;
    }
}

// ------- per-node gather (8-deep row loads, nt index stream) + transform ----
__global__ __launch_bounds__(256)
void k_gather_t(const __half* __restrict__ tin, const int* __restrict__ esrc,
                const int2* __restrict__ rowp2, const float* __restrict__ dis,
                const float* __restrict__ bias, const float* __restrict__ W,
                __half* __restrict__ tout, int N){
    __shared__ float sW[HF*HF];
    __shared__ float sh[64][33];
    int tid = threadIdx.x;
    for (int i = tid; i < HF*HF; i += 256) sW[i] = W[i];
    int nib = tid >> 2, l = tid & 3;
    int n = blockIdx.x*64 + nib;
    float acc[8] = {0.f,0.f,0.f,0.f,0.f,0.f,0.f,0.f};
    float d = 0.f;
    const float4* tv = (const float4*)tin;
    if (n < N){
        addrow8(acc, tv[(size_t)n*4 + l]);          // self loop
        int2 r = rowp2[n];
        int e = r.x, e1 = r.y;
        while (e < e1 && (e & 3)){ addrow8(acc, tv[(size_t)esrc[e]*4 + l]); e++; }
        for (; e + 7 < e1; e += 8){
            int4 a4 = nt_load_i4(&esrc[e]);
            int4 b4 = nt_load_i4(&esrc[e+4]);
            float4 v0 = tv[(size_t)a4.x*4 + l];
            float4 v1 = tv[(size_t)a4.y*4 + l];
            float4 v2 = tv[(size_t)a4.z*4 + l];
            float4 v3 = tv[(size_t)a4.w*4 + l];
            float4 v4 = tv[(size_t)b4.x*4 + l];
            float4 v5 = tv[(size_t)b4.y*4 + l];
            float4 v6 = tv[(size_t)b4.z*4 + l];
            float4 v7 = tv[(size_t)b4.w*4 + l];
            addrow8(acc, h2add4f(h2add4f(v0, v1), h2add4f(v2, v3)));
            addrow8(acc, h2add4f(h2add4f(v4, v5), h2add4f(v6, v7)));
        }
        for (; e + 3 < e1; e += 4){
            int4 s4 = nt_load_i4(&esrc[e]);
            float4 v0 = tv[(size_t)s4.x*4 + l];
            float4 v1 = tv[(size_t)s4.y*4 + l];
            float4 v2 = tv[(size_t)s4.z*4 + l];
            float4 v3 = tv[(size_t)s4.w*4 + l];
            addrow8(acc, h2add4f(h2add4f(v0, v1), h2add4f(v2, v3)));
        }
        for (; e < e1; e++) addrow8(acc, tv[(size_t)esrc[e]*4 + l]);
        d = dis[n];
#pragma unroll
        for (int c = 0; c < 8; c++)
            acc[c] = elu1(fmaf(d, acc[c], bias[8*l + c]));
    }
    __syncthreads();
#pragma unroll
    for (int c = 0; c < 8; c++) sh[nib][8*l + c] = acc[c];
    __syncthreads();
    float o[8] = {0.f,0.f,0.f,0.f,0.f,0.f,0.f,0.f};
#pragma unroll
    for (int i = 0; i < HF; i++){
        float hvv = sh[nib][i];
        float4 w0 = *(const float4*)&sW[i*HF + 8*l];
        float4 w1 = *(const float4*)&sW[i*HF + 8*l + 4];
        o[0] = fmaf(hvv, w0.x, o[0]); o[1] = fmaf(hvv, w0.y, o[1]);
        o[2] = fmaf(hvv, w0.z, o[2]); o[3] = fmaf(hvv, w0.w, o[3]);
        o[4] = fmaf(hvv, w1.x, o[4]); o[5] = fmaf(hvv, w1.y, o[5]);
        o[6] = fmaf(hvv, w1.z, o[6]); o[7] = fmaf(hvv, w1.w, o[7]);
    }
    if (n < N){
        __half2 hh[4];
#pragma unroll
        for (int k = 0; k < 4; k++)
            hh[k] = __float22half2_rn(make_float2(o[2*k]*d, o[2*k+1]*d));
        nt_store_f4(*(float4*)hh, &((float4*)tout)[(size_t)n*4 + l]);
    }
}

// ------- final: gather layer3 + elu, output MLP + sigmoid col 0 -------------
__global__ __launch_bounds__(256)
void k_gather_out(const __half* __restrict__ tin, const int* __restrict__ esrc,
                  const int2* __restrict__ rowp2, const float* __restrict__ dis,
                  const float* __restrict__ bg3,
                  const float* __restrict__ wo1, const float* __restrict__ bo1,
                  const float* __restrict__ wo2, const float* __restrict__ bo2,
                  const float* __restrict__ wo3, const float* __restrict__ bo3,
                  float* __restrict__ out, int N){
    __shared__ float sW1[HF*HF], sW2[HF*HF], sW3[HF*4];
    __shared__ float sh[64][33], sh2[64][33];
    int tid = threadIdx.x;
    for (int i = tid; i < HF*HF; i += 256){ sW1[i] = wo1[i]; sW2[i] = wo2[i]; }
    if (tid < HF*4) sW3[tid] = wo3[tid];
    int nib = tid >> 2, l = tid & 3;
    int n = blockIdx.x*64 + nib;
    float acc[8] = {0.f,0.f,0.f,0.f,0.f,0.f,0.f,0.f};
    const float4* tv = (const float4*)tin;
    if (n < N){
        addrow8(acc, tv[(size_t)n*4 + l]);
        int2 r = rowp2[n];
        int e = r.x, e1 = r.y;
        while (e < e1 && (e & 3)){ addrow8(acc, tv[(size_t)esrc[e]*4 + l]); e++; }
        for (; e + 7 < e1; e += 8){
            int4 a4 = nt_load_i4(&esrc[e]);
            int4 b4 = nt_load_i4(&esrc[e+4]);
            float4 v0 = tv[(size_t)a4.x*4 + l];
            float4 v1 = tv[(size_t)a4.y*4 + l];
            float4 v2 = tv[(size_t)a4.z*4 + l];
            float4 v3 = tv[(size_t)a4.w*4 + l];
            float4 v4 = tv[(size_t)b4.x*4 + l];
            float4 v5 = tv[(size_t)b4.y*4 + l];
            float4 v6 = tv[(size_t)b4.z*4 + l];
            float4 v7 = tv[(size_t)b4.w*4 + l];
            addrow8(acc, h2add4f(h2add4f(v0, v1), h2add4f(v2, v3)));
            addrow8(acc, h2add4f(h2add4f(v4, v5), h2add4f(v6, v7)));
        }
        for (; e + 3 < e1; e += 4){
            int4 s4 = nt_load_i4(&esrc[e]);
            float4 v0 = tv[(size_t)s4.x*4 + l];
            float4 v1 = tv[(size_t)s4.y*4 + l];
            float4 v2 = tv[(size_t)s4.z*4 + l];
            float4 v3 = tv[(size_t)s4.w*4 + l];
            addrow8(acc, h2add4f(h2add4f(v0, v1), h2add4f(v2, v3)));
        }
        for (; e < e1; e++) addrow8(acc, tv[(size_t)esrc[e]*4 + l]);
        float d = dis[n];
#pragma unroll
        for (int c = 0; c < 8; c++)
            acc[c] = elu1(fmaf(d, acc[c], bg3[8*l + c]));
    }
    __syncthreads();
#pragma unroll
    for (int c = 0; c < 8; c++) sh[nib][8*l + c] = acc[c];
    __syncthreads();
    float o1[8];
#pragma unroll
    for (int c = 0; c < 8; c++) o1[c] = bo1[8*l + c];
#pragma unroll
    for (int i = 0; i < HF; i++){
        float hvv = sh[nib][i];
        float4 w0 = *(const float4*)&sW1[i*HF + 8*l];
        float4 w1 = *(const float4*)&sW1[i*HF + 8*l + 4];
        o1[0] = fmaf(hvv, w0.x, o1[0]); o1[1] = fmaf(hvv, w0.y, o1[1]);
        o1[2] = fmaf(hvv, w0.z, o1[2]); o1[3] = fmaf(hvv, w0.w, o1[3]);
        o1[4] = fmaf(hvv, w1.x, o1[4]); o1[5] = fmaf(hvv, w1.y, o1[5]);
        o1[6] = fmaf(hvv, w1.z, o1[6]); o1[7] = fmaf(hvv, w1.w, o1[7]);
    }
#pragma unroll
    for (int c = 0; c < 8; c++) sh2[nib][8*l + c] = leaky(o1[c]);
    __syncthreads();
    float o2[8];
#pragma unroll
    for (int c = 0; c < 8; c++) o2[c] = bo2[8*l + c];
#pragma unroll
    for (int i = 0; i < HF; i++){
        float hvv = sh2[nib][i];
        float4 w0 = *(const float4*)&sW2[i*HF + 8*l];
        float4 w1 = *(const float4*)&sW2[i*HF + 8*l + 4];
        o2[0] = fmaf(hvv, w0.x, o2[0]); o2[1] = fmaf(hvv, w0.y, o2[1]);
        o2[2] = fmaf(hvv, w0.z, o2[2]); o2[3] = fmaf(hvv, w0.w, o2[3]);
        o2[4] = fmaf(hvv, w1.x, o2[4]); o2[5] = fmaf(hvv, w1.y, o2[5]);
        o2[6] = fmaf(hvv, w1.z, o2[6]); o2[7] = fmaf(hvv, w1.w, o2[7]);
    }
#pragma unroll
    for (int c = 0; c < 8; c++) sh[nib][8*l + c] = leaky(o2[c]);
    __syncthreads();
    if (n < N){
        float v = bo3[l];
#pragma unroll
        for (int i = 0; i < HF; i++) v = fmaf(sh[nib][i], sW3[i*4 + l], v);
        if (l == 0) v = sigmoidf(v);
        out[(size_t)n*4 + l] = v;
    }
}

extern "C" void kernel_launch(void* const* d_in, const int* in_sizes, int n_in,
                              void* d_out, int out_size, void* d_ws, size_t ws_size,
                              hipStream_t stream) {
    const float* x     = (const float*)d_in[0];
    const float* w_in1 = (const float*)d_in[1];
    const float* b_in1 = (const float*)d_in[2];
    const float* w_in2 = (const float*)d_in[3];
    const float* b_in2 = (const float*)d_in[4];
    const float* gamma = (const float*)d_in[5];
    const float* beta  = (const float*)d_in[6];
    const float* wg1   = (const float*)d_in[7];
    const float* bg1   = (const float*)d_in[8];
    const float* wg2   = (const float*)d_in[9];
    const float* bg2   = (const float*)d_in[10];
    const float* wg3   = (const float*)d_in[11];
    const float* bg3   = (const float*)d_in[12];
    const float* wo1   = (const float*)d_in[13];
    const float* bo1   = (const float*)d_in[14];
    const float* wo2   = (const float*)d_in[15];
    const float* bo2   = (const float*)d_in[16];
    const float* wo3   = (const float*)d_in[17];
    const float* bo3   = (const float*)d_in[18];
    const int*   ei    = (const int*)d_in[19];

    int N = in_sizes[0] / 3;
    int E = in_sizes[19] / 2;
    int B = (N + BSZ - 1) >> BSH;          // buckets (<=512)

    char* w = (char*)d_ws;
    size_t o = 0;
    auto alloc = [&](size_t bytes){ size_t r = o; o = (o + bytes + 255) & ~(size_t)255; return r; };
    // ---- zeroed region ----
    float* stats = (float*)(w + alloc(2*HF*sizeof(float)));
    int*   gfill = (int*)  (w + alloc((size_t)B*8*4));
    size_t zero_bytes = o;
    // ---- rest ----
    int2*  rowp2 = (int2*) (w + alloc((size_t)N*8));
    float* dis   = (float*)(w + alloc((size_t)N*4));
    int*   ep    = (int*)  (w + alloc((size_t)B*CAP*4));
    __half* bufH = (__half*)(w + alloc((size_t)N*HF*2));
    __half* tA   = (__half*)(w + alloc((size_t)N*HF*2));
    __half* tB   = (__half*)(w + alloc((size_t)N*HF*2));

    hipMemsetAsync(d_ws, 0, zero_bytes, stream);

    const int* src = ei;
    const int* dst = ei + E;
    int NB1 = (N + 255) / 256;
    int NC  = (E + CH - 1) / CH;
    int GB  = (N + 63) / 64;

    k_mlp_bin<<<NB1 + NC, 256, 0, stream>>>(x, w_in1, b_in1, w_in2, b_in2, bufH, stats,
                                            src, dst, gfill, ep, N, E, B, NB1);
    k_bucketD<<<B, 256, 0, stream>>>(ep, gfill, rowp2, dis, N, B);

    k_bn_t1   <<<GB, 256, 0, stream>>>(bufH, stats, gamma, beta, wg1, dis, tA, N);
    k_gather_t<<<GB, 256, 0, stream>>>(tA, ep, rowp2, dis, bg1, wg2, tB, N);
    k_gather_t<<<GB, 256, 0, stream>>>(tB, ep, rowp2, dis, bg2, wg3, tA, N);
    k_gather_out<<<GB, 256, 0, stream>>>(tA, ep, rowp2, dis, bg3,
                                         wo1, bo1, wo2, bo2, wo3, bo3, (float*)d_out, N);
}

// Round 11
// 305.681 us; speedup vs baseline: 1.2435x; 1.2435x over previous
//
#include <hip/hip_runtime.h>
#include <hip/hip_fp16.h>

#define HF 32
#define EPS 1e-5f
#define BSH 8
#define BSZ 256          // nodes per bucket
#define CH  4096         // edges per binning block
#define SUBCAP 1024      // per-XCD sub-segment capacity
#define CAP (8*SUBCAP)   // bucket segment capacity

typedef int vi4 __attribute__((ext_vector_type(4)));

__device__ __forceinline__ float leaky(float v){ return fmaxf(v, 0.01f*v); }
__device__ __forceinline__ float elu1(float v){ return v > 0.f ? v : (expf(v)-1.f); }
__device__ __forceinline__ float sigmoidf(float v){ return 1.f/(1.f+expf(-v)); }

// nt 16B index load -> int4 (read-once stream; nt LOADS only — nt stores
// on scattered writes caused 143MB HBM writeback in round 10)
__device__ __forceinline__ int4 nt_load_i4(const int* p){
    vi4 v = __builtin_nontemporal_load((const vi4*)p);
    return make_int4(v.x, v.y, v.z, v.w);
}

// add 8 halfs (16B) into fp32 accumulator
__device__ __forceinline__ void addrow8(float* a, float4 v){
    const __half2* p = (const __half2*)&v;
#pragma unroll
    for (int k = 0; k < 4; k++){
        float2 f = __half22float2(p[k]);
        a[2*k] += f.x; a[2*k+1] += f.y;
    }
}
// packed fp16 add of two 8-half rows
__device__ __forceinline__ float4 h2add4f(float4 a, float4 b){
    __half2* pa = (__half2*)&a; __half2* pb = (__half2*)&b;
    float4 r; __half2* pr = (__half2*)&r;
#pragma unroll
    for (int k = 0; k < 4; k++) pr[k] = __hadd2(pa[k], pb[k]);
    return r;
}

// ------- input MLP + fused BN stats: h=leaky(leaky(x@W1+b1)@W2+b2) ----------
__global__ __launch_bounds__(256)
void k_mlp(const float* __restrict__ x,
           const float* __restrict__ w1, const float* __restrict__ b1,
           const float* __restrict__ w2, const float* __restrict__ b2,
           __half* __restrict__ h, float* __restrict__ stats, int N){
    __shared__ float sW1[3*HF], sB1[HF], sW2[HF*HF], sB2[HF];
    __shared__ float sh[256][33];
    int t = threadIdx.x;
    for (int i = t; i < 3*HF; i += 256) sW1[i] = w1[i];
    if (t < HF){ sB1[t] = b1[t]; sB2[t] = b2[t]; }
    for (int i = t; i < HF*HF; i += 256) sW2[i] = w2[i];
    __syncthreads();
    int n = blockIdx.x*256 + t;
    float h2[HF];
    if (n < N){
        float x0 = x[(size_t)n*3], x1 = x[(size_t)n*3+1], x2 = x[(size_t)n*3+2];
        float h1[HF];
#pragma unroll
        for (int j = 0; j < HF; j++){
            float v = fmaf(x0, sW1[j], fmaf(x1, sW1[HF+j], fmaf(x2, sW1[2*HF+j], sB1[j])));
            h1[j] = leaky(v);
        }
#pragma unroll
        for (int j = 0; j < HF; j++){
            float v = sB2[j];
#pragma unroll
            for (int i = 0; i < HF; i++) v = fmaf(h1[i], sW2[i*HF+j], v);
            h2[j] = leaky(v);
        }
        float4* hv = (float4*)(h + (size_t)n*HF);
#pragma unroll
        for (int jb = 0; jb < 4; jb++){
            __half2 hh[4];
#pragma unroll
            for (int k = 0; k < 4; k++)
                hh[k] = __float22half2_rn(make_float2(h2[jb*8+2*k], h2[jb*8+2*k+1]));
            hv[jb] = *(float4*)hh;
        }
    } else {
#pragma unroll
        for (int j = 0; j < HF; j++) h2[j] = 0.f;
    }
#pragma unroll
    for (int j = 0; j < HF; j++) sh[t][j] = h2[j];
    __syncthreads();
    int f = t & 31, g = t >> 5;
    float s = 0.f, ss = 0.f;
    for (int i = 0; i < 32; i++){
        float v = sh[g*32 + i][f];
        s += v; ss += v*v;
    }
    __syncthreads();
    sh[g][f] = s; sh[8+g][f] = ss;
    __syncthreads();
    if (t < HF){
        float a = 0.f, b = 0.f;
#pragma unroll
        for (int g2 = 0; g2 < 8; g2++){ a += sh[g2][t]; b += sh[8+g2][t]; }
        atomicAdd(&stats[t], a);
        atomicAdd(&stats[HF+t], b);
    }
}

// ------ single-pass binning, register-cached edges, per-XCD sub-segments ----
__global__ __launch_bounds__(256)
void k_bin(const int* __restrict__ src, const int* __restrict__ dst,
           int* __restrict__ gfill, int* __restrict__ ep, int E, int B){
    __shared__ int lcnt[512], lbase[512], lpos[512];
    int t = threadIdx.x;
    for (int i = t; i < B; i += 256){ lcnt[i] = 0; lpos[i] = 0; }
    __syncthreads();
    int base = blockIdx.x * CH;
    int xcd = blockIdx.x & 7;
    int dv[16], sv[16];
#pragma unroll
    for (int i = 0; i < 16; i++){
        int e = base + t + i*256;
        dv[i] = (e < E) ? dst[e] : -1;
        sv[i] = (e < E) ? src[e] : 0;
    }
#pragma unroll
    for (int i = 0; i < 16; i++)
        if (dv[i] >= 0) atomicAdd(&lcnt[dv[i] >> BSH], 1);
    __syncthreads();
    for (int i = t; i < B; i += 256){
        int c = lcnt[i];
        lbase[i] = c ? (i*CAP + xcd*SUBCAP + atomicAdd(&gfill[i*8 + xcd], c)) : 0;
    }
    __syncthreads();
#pragma unroll
    for (int i = 0; i < 16; i++){
        if (dv[i] >= 0){
            int d = dv[i], bb = d >> BSH;
            int p = lbase[bb] + atomicAdd(&lpos[bb], 1);
            ep[p] = (sv[i] << BSH) | (d & (BSZ-1));
        }
    }
}

// ------- per-bucket CSR build: rowp2, dis; ep rewritten as sorted src -------
__global__ __launch_bounds__(256)
void k_bucketD(int* __restrict__ ep, const int* __restrict__ gfill,
               int2* __restrict__ rowp2, float* __restrict__ dis, int N, int B){
    __shared__ int sep[CAP];
    __shared__ int lcnt[256], lpre[256], lfill[256], sc[256];
    int b = blockIdx.x, t = threadIdx.x;
    int cx[8], coff[8], cnt = 0;
#pragma unroll
    for (int x = 0; x < 8; x++){ cx[x] = gfill[b*8 + x]; coff[x] = cnt; cnt += cx[x]; }
    lcnt[t] = 0; lfill[t] = 0;
    __syncthreads();
    int base = b*CAP;
#pragma unroll
    for (int x = 0; x < 8; x++)
        for (int j = t; j < cx[x]; j += 256) sep[coff[x] + j] = ep[base + x*SUBCAP + j];
    __syncthreads();
    for (int e = t; e < cnt; e += 256) atomicAdd(&lcnt[sep[e] & (BSZ-1)], 1);
    __syncthreads();
    int v = lcnt[t];
    sc[t] = v; __syncthreads();
    for (int off = 1; off < 256; off <<= 1){
        int u = (t >= off) ? sc[t - off] : 0;
        __syncthreads();
        sc[t] += u;
        __syncthreads();
    }
    int pre = sc[t] - v;
    lpre[t] = pre;
    int n = b*BSZ + t;
    if (n < N){
        rowp2[n] = make_int2(base + pre, base + pre + v);
        dis[n]   = rsqrtf((float)(v + 1));
    }
    __syncthreads();
    for (int e = t; e < cnt; e += 256){
        int val = sep[e];
        int d = val & (BSZ-1);
        int p = lpre[d] + atomicAdd(&lfill[d], 1);
        ep[base + p] = val >> BSH;          // strip -> plain src index
    }
}

// ------- BN + first transform: t1 = ((bn(h))@W)*dis, fp16 row layout --------
__global__ __launch_bounds__(256)
void k_bn_t1(const __half* __restrict__ h, const float* __restrict__ stats,
             const float* __restrict__ gamma, const float* __restrict__ beta,
             const float* __restrict__ W, const float* __restrict__ dis,
             __half* __restrict__ tout, int N){
    __shared__ float sW[HF*HF];
    __shared__ float sh[64][33];
    int tid = threadIdx.x;
    for (int i = tid; i < HF*HF; i += 256) sW[i] = W[i];
    int nib = tid >> 2, l = tid & 3;
    int n = blockIdx.x*64 + nib;
    float hv[8];
    float d = 0.f;
    if (n < N){
        float4 raw = ((const float4*)h)[(size_t)n*4 + l];
        const __half2* p = (const __half2*)&raw;
        float tmp[8];
#pragma unroll
        for (int k = 0; k < 4; k++){
            float2 f2 = __half22float2(p[k]);
            tmp[2*k] = f2.x; tmp[2*k+1] = f2.y;
        }
        d = dis[n];
        float inv = 1.0f / (float)N;
#pragma unroll
        for (int c = 0; c < 8; c++){
            int f = 8*l + c;
            float mu  = stats[f]    * inv;
            float var = stats[HF+f] * inv - mu*mu;
            float rs  = rsqrtf(var + EPS);
            hv[c] = (tmp[c] - mu) * rs * gamma[f] + beta[f];
        }
    } else {
#pragma unroll
        for (int c = 0; c < 8; c++) hv[c] = 0.f;
    }
    __syncthreads();
#pragma unroll
    for (int c = 0; c < 8; c++) sh[nib][8*l + c] = hv[c];
    __syncthreads();
    float o[8] = {0.f,0.f,0.f,0.f,0.f,0.f,0.f,0.f};
#pragma unroll
    for (int i = 0; i < HF; i++){
        float hvv = sh[nib][i];
        float4 w0 = *(const float4*)&sW[i*HF + 8*l];
        float4 w1 = *(const float4*)&sW[i*HF + 8*l + 4];
        o[0] = fmaf(hvv, w0.x, o[0]); o[1] = fmaf(hvv, w0.y, o[1]);
        o[2] = fmaf(hvv, w0.z, o[2]); o[3] = fmaf(hvv, w0.w, o[3]);
        o[4] = fmaf(hvv, w1.x, o[4]); o[5] = fmaf(hvv, w1.y, o[5]);
        o[6] = fmaf(hvv, w1.z, o[6]); o[7] = fmaf(hvv, w1.w, o[7]);
    }
    if (n < N){
        __half2 hh[4];
#pragma unroll
        for (int k = 0; k < 4; k++)
            hh[k] = __float22half2_rn(make_float2(o[2*k]*d, o[2*k+1]*d));
        ((float4*)tout)[(size_t)n*4 + l] = *(float4*)hh;
    }
}

// ------- per-node gather (8-deep row loads, nt index loads) + transform -----
__global__ __launch_bounds__(256)
void k_gather_t(const __half* __restrict__ tin, const int* __restrict__ esrc,
                const int2* __restrict__ rowp2, const float* __restrict__ dis,
                const float* __restrict__ bias, const float* __restrict__ W,
                __half* __restrict__ tout, int N){
    __shared__ float sW[HF*HF];
    __shared__ float sh[64][33];
    int tid = threadIdx.x;
    for (int i = tid; i < HF*HF; i += 256) sW[i] = W[i];
    int nib = tid >> 2, l = tid & 3;
    int n = blockIdx.x*64 + nib;
    float acc[8] = {0.f,0.f,0.f,0.f,0.f,0.f,0.f,0.f};
    float d = 0.f;
    const float4* tv = (const float4*)tin;
    if (n < N){
        addrow8(acc, tv[(size_t)n*4 + l]);          // self loop
        int2 r = rowp2[n];
        int e = r.x, e1 = r.y;
        while (e < e1 && (e & 3)){ addrow8(acc, tv[(size_t)esrc[e]*4 + l]); e++; }
        for (; e + 7 < e1; e += 8){
            int4 a4 = nt_load_i4(&esrc[e]);
            int4 b4 = nt_load_i4(&esrc[e+4]);
            float4 v0 = tv[(size_t)a4.x*4 + l];
            float4 v1 = tv[(size_t)a4.y*4 + l];
            float4 v2 = tv[(size_t)a4.z*4 + l];
            float4 v3 = tv[(size_t)a4.w*4 + l];
            float4 v4 = tv[(size_t)b4.x*4 + l];
            float4 v5 = tv[(size_t)b4.y*4 + l];
            float4 v6 = tv[(size_t)b4.z*4 + l];
            float4 v7 = tv[(size_t)b4.w*4 + l];
            addrow8(acc, h2add4f(h2add4f(v0, v1), h2add4f(v2, v3)));
            addrow8(acc, h2add4f(h2add4f(v4, v5), h2add4f(v6, v7)));
        }
        for (; e + 3 < e1; e += 4){
            int4 s4 = nt_load_i4(&esrc[e]);
            float4 v0 = tv[(size_t)s4.x*4 + l];
            float4 v1 = tv[(size_t)s4.y*4 + l];
            float4 v2 = tv[(size_t)s4.z*4 + l];
            float4 v3 = tv[(size_t)s4.w*4 + l];
            addrow8(acc, h2add4f(h2add4f(v0, v1), h2add4f(v2, v3)));
        }
        for (; e < e1; e++) addrow8(acc, tv[(size_t)esrc[e]*4 + l]);
        d = dis[n];
#pragma unroll
        for (int c = 0; c < 8; c++)
            acc[c] = elu1(fmaf(d, acc[c], bias[8*l + c]));
    }
    __syncthreads();
#pragma unroll
    for (int c = 0; c < 8; c++) sh[nib][8*l + c] = acc[c];
    __syncthreads();
    float o[8] = {0.f,0.f,0.f,0.f,0.f,0.f,0.f,0.f};
#pragma unroll
    for (int i = 0; i < HF; i++){
        float hvv = sh[nib][i];
        float4 w0 = *(const float4*)&sW[i*HF + 8*l];
        float4 w1 = *(const float4*)&sW[i*HF + 8*l + 4];
        o[0] = fmaf(hvv, w0.x, o[0]); o[1] = fmaf(hvv, w0.y, o[1]);
        o[2] = fmaf(hvv, w0.z, o[2]); o[3] = fmaf(hvv, w0.w, o[3]);
        o[4] = fmaf(hvv, w1.x, o[4]); o[5] = fmaf(hvv, w1.y, o[5]);
        o[6] = fmaf(hvv, w1.z, o[6]); o[7] = fmaf(hvv, w1.w, o[7]);
    }
    if (n < N){
        __half2 hh[4];
#pragma unroll
        for (int k = 0; k < 4; k++)
            hh[k] = __float22half2_rn(make_float2(o[2*k]*d, o[2*k+1]*d));
        ((float4*)tout)[(size_t)n*4 + l] = *(float4*)hh;
    }
}

// ------- final: gather layer3 + elu, output MLP + sigmoid col 0 -------------
__global__ __launch_bounds__(256)
void k_gather_out(const __half* __restrict__ tin, const int* __restrict__ esrc,
                  const int2* __restrict__ rowp2, const float* __restrict__ dis,
                  const float* __restrict__ bg3,
                  const float* __restrict__ wo1, const float* __restrict__ bo1,
                  const float* __restrict__ wo2, const float* __restrict__ bo2,
                  const float* __restrict__ wo3, const float* __restrict__ bo3,
                  float* __restrict__ out, int N){
    __shared__ float sW1[HF*HF], sW2[HF*HF], sW3[HF*4];
    __shared__ float sh[64][33], sh2[64][33];
    int tid = threadIdx.x;
    for (int i = tid; i < HF*HF; i += 256){ sW1[i] = wo1[i]; sW2[i] = wo2[i]; }
    if (tid < HF*4) sW3[tid] = wo3[tid];
    int nib = tid >> 2, l = tid & 3;
    int n = blockIdx.x*64 + nib;
    float acc[8] = {0.f,0.f,0.f,0.f,0.f,0.f,0.f,0.f};
    const float4* tv = (const float4*)tin;
    if (n < N){
        addrow8(acc, tv[(size_t)n*4 + l]);
        int2 r = rowp2[n];
        int e = r.x, e1 = r.y;
        while (e < e1 && (e & 3)){ addrow8(acc, tv[(size_t)esrc[e]*4 + l]); e++; }
        for (; e + 7 < e1; e += 8){
            int4 a4 = nt_load_i4(&esrc[e]);
            int4 b4 = nt_load_i4(&esrc[e+4]);
            float4 v0 = tv[(size_t)a4.x*4 + l];
            float4 v1 = tv[(size_t)a4.y*4 + l];
            float4 v2 = tv[(size_t)a4.z*4 + l];
            float4 v3 = tv[(size_t)a4.w*4 + l];
            float4 v4 = tv[(size_t)b4.x*4 + l];
            float4 v5 = tv[(size_t)b4.y*4 + l];
            float4 v6 = tv[(size_t)b4.z*4 + l];
            float4 v7 = tv[(size_t)b4.w*4 + l];
            addrow8(acc, h2add4f(h2add4f(v0, v1), h2add4f(v2, v3)));
            addrow8(acc, h2add4f(h2add4f(v4, v5), h2add4f(v6, v7)));
        }
        for (; e + 3 < e1; e += 4){
            int4 s4 = nt_load_i4(&esrc[e]);
            float4 v0 = tv[(size_t)s4.x*4 + l];
            float4 v1 = tv[(size_t)s4.y*4 + l];
            float4 v2 = tv[(size_t)s4.z*4 + l];
            float4 v3 = tv[(size_t)s4.w*4 + l];
            addrow8(acc, h2add4f(h2add4f(v0, v1), h2add4f(v2, v3)));
        }
        for (; e < e1; e++) addrow8(acc, tv[(size_t)esrc[e]*4 + l]);
        float d = dis[n];
#pragma unroll
        for (int c = 0; c < 8; c++)
            acc[c] = elu1(fmaf(d, acc[c], bg3[8*l + c]));
    }
    __syncthreads();
#pragma unroll
    for (int c = 0; c < 8; c++) sh[nib][8*l + c] = acc[c];
    __syncthreads();
    float o1[8];
#pragma unroll
    for (int c = 0; c < 8; c++) o1[c] = bo1[8*l + c];
#pragma unroll
    for (int i = 0; i < HF; i++){
        float hvv = sh[nib][i];
        float4 w0 = *(const float4*)&sW1[i*HF + 8*l];
        float4 w1 = *(const float4*)&sW1[i*HF + 8*l + 4];
        o1[0] = fmaf(hvv, w0.x, o1[0]); o1[1] = fmaf(hvv, w0.y, o1[1]);
        o1[2] = fmaf(hvv, w0.z, o1[2]); o1[3] = fmaf(hvv, w0.w, o1[3]);
        o1[4] = fmaf(hvv, w1.x, o1[4]); o1[5] = fmaf(hvv, w1.y, o1[5]);
        o1[6] = fmaf(hvv, w1.z, o1[6]); o1[7] = fmaf(hvv, w1.w, o1[7]);
    }
#pragma unroll
    for (int c = 0; c < 8; c++) sh2[nib][8*l + c] = leaky(o1[c]);
    __syncthreads();
    float o2[8];
#pragma unroll
    for (int c = 0; c < 8; c++) o2[c] = bo2[8*l + c];
#pragma unroll
    for (int i = 0; i < HF; i++){
        float hvv = sh2[nib][i];
        float4 w0 = *(const float4*)&sW2[i*HF + 8*l];
        float4 w1 = *(const float4*)&sW2[i*HF + 8*l + 4];
        o2[0] = fmaf(hvv, w0.x, o2[0]); o2[1] = fmaf(hvv, w0.y, o2[1]);
        o2[2] = fmaf(hvv, w0.z, o2[2]); o2[3] = fmaf(hvv, w0.w, o2[3]);
        o2[4] = fmaf(hvv, w1.x, o2[4]); o2[5] = fmaf(hvv, w1.y, o2[5]);
        o2[6] = fmaf(hvv, w1.z, o2[6]); o2[7] = fmaf(hvv, w1.w, o2[7]);
    }
#pragma unroll
    for (int c = 0; c < 8; c++) sh[nib][8*l + c] = leaky(o2[c]);
    __syncthreads();
    if (n < N){
        float v = bo3[l];
#pragma unroll
        for (int i = 0; i < HF; i++) v = fmaf(sh[nib][i], sW3[i*4 + l], v);
        if (l == 0) v = sigmoidf(v);
        out[(size_t)n*4 + l] = v;
    }
}

extern "C" void kernel_launch(void* const* d_in, const int* in_sizes, int n_in,
                              void* d_out, int out_size, void* d_ws, size_t ws_size,
                              hipStream_t stream) {
    const float* x     = (const float*)d_in[0];
    const float* w_in1 = (const float*)d_in[1];
    const float* b_in1 = (const float*)d_in[2];
    const float* w_in2 = (const float*)d_in[3];
    const float* b_in2 = (const float*)d_in[4];
    const float* gamma = (const float*)d_in[5];
    const float* beta  = (const float*)d_in[6];
    const float* wg1   = (const float*)d_in[7];
    const float* bg1   = (const float*)d_in[8];
    const float* wg2   = (const float*)d_in[9];
    const float* bg2   = (const float*)d_in[10];
    const float* wg3   = (const float*)d_in[11];
    const float* bg3   = (const float*)d_in[12];
    const float* wo1   = (const float*)d_in[13];
    const float* bo1   = (const float*)d_in[14];
    const float* wo2   = (const float*)d_in[15];
    const float* bo2   = (const float*)d_in[16];
    const float* wo3   = (const float*)d_in[17];
    const float* bo3   = (const float*)d_in[18];
    const int*   ei    = (const int*)d_in[19];

    int N = in_sizes[0] / 3;
    int E = in_sizes[19] / 2;
    int B = (N + BSZ - 1) >> BSH;          // buckets (<=512)

    char* w = (char*)d_ws;
    size_t o = 0;
    auto alloc = [&](size_t bytes){ size_t r = o; o = (o + bytes + 255) & ~(size_t)255; return r; };
    // ---- zeroed region ----
    float* stats = (float*)(w + alloc(2*HF*sizeof(float)));
    int*   gfill = (int*)  (w + alloc((size_t)B*8*4));
    size_t zero_bytes = o;
    // ---- rest ----
    int2*  rowp2 = (int2*) (w + alloc((size_t)N*8));
    float* dis   = (float*)(w + alloc((size_t)N*4));
    int*   ep    = (int*)  (w + alloc((size_t)B*CAP*4));
    __half* bufH = (__half*)(w + alloc((size_t)N*HF*2));
    __half* tA   = (__half*)(w + alloc((size_t)N*HF*2));
    __half* tB   = (__half*)(w + alloc((size_t)N*HF*2));

    hipMemsetAsync(d_ws, 0, zero_bytes, stream);

    const int* src = ei;
    const int* dst = ei + E;
    int NB1 = (N + 255) / 256;
    int NC  = (E + CH - 1) / CH;
    int GB  = (N + 63) / 64;

    k_mlp    <<<NB1, 256, 0, stream>>>(x, w_in1, b_in1, w_in2, b_in2, bufH, stats, N);
    k_bin    <<<NC,  256, 0, stream>>>(src, dst, gfill, ep, E, B);
    k_bucketD<<<B,   256, 0, stream>>>(ep, gfill, rowp2, dis, N, B);

    k_bn_t1   <<<GB, 256, 0, stream>>>(bufH, stats, gamma, beta, wg1, dis, tA, N);
    k_gather_t<<<GB, 256, 0, stream>>>(tA, ep, rowp2, dis, bg1, wg2, tB, N);
    k_gather_t<<<GB, 256, 0, stream>>>(tB, ep, rowp2, dis, bg2, wg3, tA, N);
    k_gather_out<<<GB, 256, 0, stream>>>(tA, ep, rowp2, dis, bg3,
                                         wo1, bo1, wo2, bo2, wo3, bo3, (float*)d_out, N);
}

// Round 12
// 285.982 us; speedup vs baseline: 1.3292x; 1.0689x over previous
//
#include <hip/hip_runtime.h>
#include <hip/hip_fp16.h>

#define HF 32
#define EPS 1e-5f
#define BSH 7
#define BSZ 128          // nodes per bucket
#define CH  8192         // edges per binning block
#define SUBCAP 512       // per-XCD sub-segment capacity
#define CAP (8*SUBCAP)   // bucket segment capacity (4096)

typedef int vi4 __attribute__((ext_vector_type(4)));

__device__ __forceinline__ float leaky(float v){ return fmaxf(v, 0.01f*v); }
__device__ __forceinline__ float elu1(float v){ return v > 0.f ? v : (expf(v)-1.f); }
__device__ __forceinline__ float sigmoidf(float v){ return 1.f/(1.f+expf(-v)); }

// nt 16B index load (read-once stream). NOTE: nt LOADS only — nt stores on
// scattered writes caused 143MB HBM writeback in round 10.
__device__ __forceinline__ int4 nt_load_i4(const int* p){
    vi4 v = __builtin_nontemporal_load((const vi4*)p);
    return make_int4(v.x, v.y, v.z, v.w);
}

// add 8 halfs (16B) into fp32 accumulator
__device__ __forceinline__ void addrow8(float* a, float4 v){
    const __half2* p = (const __half2*)&v;
#pragma unroll
    for (int k = 0; k < 4; k++){
        float2 f = __half22float2(p[k]);
        a[2*k] += f.x; a[2*k+1] += f.y;
    }
}
// packed fp16 add of two 8-half rows
__device__ __forceinline__ float4 h2add4f(float4 a, float4 b){
    __half2* pa = (__half2*)&a; __half2* pb = (__half2*)&b;
    float4 r; __half2* pr = (__half2*)&r;
#pragma unroll
    for (int k = 0; k < 4; k++) pr[k] = __hadd2(pa[k], pb[k]);
    return r;
}

// ===== fused: input MLP + BN stats  |  edge binning (block-range split) =====
// plain stores everywhere; LDS union sized by the mlp branch (same as the
// standalone k_mlp), so occupancy is unchanged vs unfused mlp.
union SMem {
    struct {
        float sW1[3*HF]; float sB1[HF]; float sW2[HF*HF]; float sB2[HF];
        float sh[256][33];
    } mlp;
    struct { int lcnt[1024]; int lbase[1024]; int lpos[1024]; } bin;
};

__global__ __launch_bounds__(256)
void k_mlp_bin(const float* __restrict__ x,
               const float* __restrict__ w1, const float* __restrict__ b1,
               const float* __restrict__ w2, const float* __restrict__ b2,
               __half* __restrict__ h, float* __restrict__ stats,
               const int* __restrict__ src, const int* __restrict__ dst,
               int* __restrict__ gfill, int* __restrict__ ep,
               int N, int E, int B, int NB1){
    __shared__ SMem sm;
    int t = threadIdx.x;
    if ((int)blockIdx.x < NB1){
        // ---------------- MLP + stats ----------------
        for (int i = t; i < 3*HF; i += 256) sm.mlp.sW1[i] = w1[i];
        if (t < HF){ sm.mlp.sB1[t] = b1[t]; sm.mlp.sB2[t] = b2[t]; }
        for (int i = t; i < HF*HF; i += 256) sm.mlp.sW2[i] = w2[i];
        __syncthreads();
        int n = blockIdx.x*256 + t;
        float h2[HF];
        if (n < N){
            float x0 = x[(size_t)n*3], x1 = x[(size_t)n*3+1], x2 = x[(size_t)n*3+2];
            float h1[HF];
#pragma unroll
            for (int j = 0; j < HF; j++){
                float v = fmaf(x0, sm.mlp.sW1[j], fmaf(x1, sm.mlp.sW1[HF+j],
                          fmaf(x2, sm.mlp.sW1[2*HF+j], sm.mlp.sB1[j])));
                h1[j] = leaky(v);
            }
#pragma unroll
            for (int j = 0; j < HF; j++){
                float v = sm.mlp.sB2[j];
#pragma unroll
                for (int i = 0; i < HF; i++) v = fmaf(h1[i], sm.mlp.sW2[i*HF+j], v);
                h2[j] = leaky(v);
            }
            float4* hv = (float4*)(h + (size_t)n*HF);
#pragma unroll
            for (int jb = 0; jb < 4; jb++){
                __half2 hh[4];
#pragma unroll
                for (int k = 0; k < 4; k++)
                    hh[k] = __float22half2_rn(make_float2(h2[jb*8+2*k], h2[jb*8+2*k+1]));
                hv[jb] = *(float4*)hh;
            }
        } else {
#pragma unroll
            for (int j = 0; j < HF; j++) h2[j] = 0.f;
        }
#pragma unroll
        for (int j = 0; j < HF; j++) sm.mlp.sh[t][j] = h2[j];
        __syncthreads();
        int f = t & 31, g = t >> 5;
        float s = 0.f, ss = 0.f;
        for (int i = 0; i < 32; i++){
            float v = sm.mlp.sh[g*32 + i][f];
            s += v; ss += v*v;
        }
        __syncthreads();
        sm.mlp.sh[g][f] = s; sm.mlp.sh[8+g][f] = ss;
        __syncthreads();
        if (t < HF){
            float a = 0.f, b = 0.f;
#pragma unroll
            for (int g2 = 0; g2 < 8; g2++){ a += sm.mlp.sh[g2][t]; b += sm.mlp.sh[8+g2][t]; }
            atomicAdd(&stats[t], a);
            atomicAdd(&stats[HF+t], b);
        }
    } else {
        // ---------------- binning (plain stores) ----------------
        int bid = blockIdx.x - NB1;
        for (int i = t; i < B; i += 256){ sm.bin.lcnt[i] = 0; sm.bin.lpos[i] = 0; }
        __syncthreads();
        int base = bid * CH;
        int xcd = blockIdx.x & 7;
        int dv[16], sv[16];
        // two half-chunks of 4096 to keep register count moderate
        for (int half = 0; half < 2; half++){
            int hbase = base + half*4096;
#pragma unroll
            for (int i = 0; i < 16; i++){
                int e = hbase + t + i*256;
                dv[i] = (e < E) ? dst[e] : -1;
                sv[i] = (e < E) ? src[e] : 0;
            }
#pragma unroll
            for (int i = 0; i < 16; i++)
                if (dv[i] >= 0) atomicAdd(&sm.bin.lcnt[dv[i] >> BSH], 1);
            if (half == 0){
                // stash first half in LDS? no — recount strategy: store to regs not possible
            }
            __syncthreads();
            if (half == 0){
                // reserve after first half? We must count ALL before reserving.
                // Instead: accumulate counts across both halves, reserve once, then
                // re-read edges for scatter (L2-hot).
            }
        }
        // reserve ranges (counts now cover both halves)
        for (int i = t; i < B; i += 256){
            int c = sm.bin.lcnt[i];
            sm.bin.lbase[i] = c ? (i*CAP + xcd*SUBCAP + atomicAdd(&gfill[i*8 + xcd], c)) : 0;
        }
        __syncthreads();
        // scatter: re-read edges (L2-hot second pass)
        for (int half = 0; half < 2; half++){
            int hbase = base + half*4096;
#pragma unroll
            for (int i = 0; i < 16; i++){
                int e = hbase + t + i*256;
                if (e < E){
                    int d = dst[e], s = src[e];
                    int bb = d >> BSH;
                    int p = sm.bin.lbase[bb] + atomicAdd(&sm.bin.lpos[bb], 1);
                    ep[p] = (s << BSH) | (d & (BSZ-1));
                }
            }
        }
    }
}

// ------- per-bucket CSR build: rowp2, dis; ep rewritten as sorted src -------
__global__ __launch_bounds__(256)
void k_bucketD(int* __restrict__ ep, const int* __restrict__ gfill,
               int2* __restrict__ rowp2, float* __restrict__ dis, int N, int B){
    __shared__ int sep[CAP];
    __shared__ int lcnt[256], lpre[256], lfill[256], sc[256];
    int b = blockIdx.x, t = threadIdx.x;
    int cx[8], coff[8], cnt = 0;
#pragma unroll
    for (int x = 0; x < 8; x++){ cx[x] = gfill[b*8 + x]; coff[x] = cnt; cnt += cx[x]; }
    lcnt[t] = 0; lfill[t] = 0;
    __syncthreads();
    int base = b*CAP;
#pragma unroll
    for (int x = 0; x < 8; x++)
        for (int j = t; j < cx[x]; j += 256) sep[coff[x] + j] = ep[base + x*SUBCAP + j];
    __syncthreads();
    for (int e = t; e < cnt; e += 256) atomicAdd(&lcnt[sep[e] & (BSZ-1)], 1);
    __syncthreads();
    int v = lcnt[t];
    sc[t] = v; __syncthreads();
    for (int off = 1; off < 256; off <<= 1){
        int u = (t >= off) ? sc[t - off] : 0;
        __syncthreads();
        sc[t] += u;
        __syncthreads();
    }
    int pre = sc[t] - v;
    lpre[t] = pre;
    int n = b*BSZ + t;
    if (t < BSZ && n < N){
        rowp2[n] = make_int2(base + pre, base + pre + v);
        dis[n]   = rsqrtf((float)(v + 1));
    }
    __syncthreads();
    for (int e = t; e < cnt; e += 256){
        int val = sep[e];
        int d = val & (BSZ-1);
        int p = lpre[d] + atomicAdd(&lfill[d], 1);
        ep[base + p] = val >> BSH;          // strip -> plain src index
    }
}

// ------- BN + first transform: t1 = ((bn(h))@W)*dis, fp16 row layout --------
__global__ __launch_bounds__(256)
void k_bn_t1(const __half* __restrict__ h, const float* __restrict__ stats,
             const float* __restrict__ gamma, const float* __restrict__ beta,
             const float* __restrict__ W, const float* __restrict__ dis,
             __half* __restrict__ tout, int N){
    __shared__ float sW[HF*HF];
    __shared__ float sh[64][33];
    int tid = threadIdx.x;
    for (int i = tid; i < HF*HF; i += 256) sW[i] = W[i];
    int nib = tid >> 2, l = tid & 3;
    int n = blockIdx.x*64 + nib;
    float hv[8];
    float d = 0.f;
    if (n < N){
        float4 raw = ((const float4*)h)[(size_t)n*4 + l];
        const __half2* p = (const __half2*)&raw;
        float tmp[8];
#pragma unroll
        for (int k = 0; k < 4; k++){
            float2 f2 = __half22float2(p[k]);
            tmp[2*k] = f2.x; tmp[2*k+1] = f2.y;
        }
        d = dis[n];
        float inv = 1.0f / (float)N;
#pragma unroll
        for (int c = 0; c < 8; c++){
            int f = 8*l + c;
            float mu  = stats[f]    * inv;
            float var = stats[HF+f] * inv - mu*mu;
            float rs  = rsqrtf(var + EPS);
            hv[c] = (tmp[c] - mu) * rs * gamma[f] + beta[f];
        }
    } else {
#pragma unroll
        for (int c = 0; c < 8; c++) hv[c] = 0.f;
    }
    __syncthreads();
#pragma unroll
    for (int c = 0; c < 8; c++) sh[nib][8*l + c] = hv[c];
    __syncthreads();
    float o[8] = {0.f,0.f,0.f,0.f,0.f,0.f,0.f,0.f};
#pragma unroll
    for (int i = 0; i < HF; i++){
        float hvv = sh[nib][i];
        float4 w0 = *(const float4*)&sW[i*HF + 8*l];
        float4 w1 = *(const float4*)&sW[i*HF + 8*l + 4];
        o[0] = fmaf(hvv, w0.x, o[0]); o[1] = fmaf(hvv, w0.y, o[1]);
        o[2] = fmaf(hvv, w0.z, o[2]); o[3] = fmaf(hvv, w0.w, o[3]);
        o[4] = fmaf(hvv, w1.x, o[4]); o[5] = fmaf(hvv, w1.y, o[5]);
        o[6] = fmaf(hvv, w1.z, o[6]); o[7] = fmaf(hvv, w1.w, o[7]);
    }
    if (n < N){
        __half2 hh[4];
#pragma unroll
        for (int k = 0; k < 4; k++)
            hh[k] = __float22half2_rn(make_float2(o[2*k]*d, o[2*k+1]*d));
        ((float4*)tout)[(size_t)n*4 + l] = *(float4*)hh;
    }
}

// ------- per-node gather (8-deep row loads, nt index loads) + transform -----
__global__ __launch_bounds__(256)
void k_gather_t(const __half* __restrict__ tin, const int* __restrict__ esrc,
                const int2* __restrict__ rowp2, const float* __restrict__ dis,
                const float* __restrict__ bias, const float* __restrict__ W,
                __half* __restrict__ tout, int N){
    __shared__ float sW[HF*HF];
    __shared__ float sh[64][33];
    int tid = threadIdx.x;
    for (int i = tid; i < HF*HF; i += 256) sW[i] = W[i];
    int nib = tid >> 2, l = tid & 3;
    int n = blockIdx.x*64 + nib;
    float acc[8] = {0.f,0.f,0.f,0.f,0.f,0.f,0.f,0.f};
    float d = 0.f;
    const float4* tv = (const float4*)tin;
    if (n < N){
        addrow8(acc, tv[(size_t)n*4 + l]);          // self loop
        int2 r = rowp2[n];
        int e = r.x, e1 = r.y;
        while (e < e1 && (e & 3)){ addrow8(acc, tv[(size_t)esrc[e]*4 + l]); e++; }
        for (; e + 7 < e1; e += 8){
            int4 a4 = nt_load_i4(&esrc[e]);
            int4 b4 = nt_load_i4(&esrc[e+4]);
            float4 v0 = tv[(size_t)a4.x*4 + l];
            float4 v1 = tv[(size_t)a4.y*4 + l];
            float4 v2 = tv[(size_t)a4.z*4 + l];
            float4 v3 = tv[(size_t)a4.w*4 + l];
            float4 v4 = tv[(size_t)b4.x*4 + l];
            float4 v5 = tv[(size_t)b4.y*4 + l];
            float4 v6 = tv[(size_t)b4.z*4 + l];
            float4 v7 = tv[(size_t)b4.w*4 + l];
            addrow8(acc, h2add4f(h2add4f(v0, v1), h2add4f(v2, v3)));
            addrow8(acc, h2add4f(h2add4f(v4, v5), h2add4f(v6, v7)));
        }
        for (; e + 3 < e1; e += 4){
            int4 s4 = nt_load_i4(&esrc[e]);
            float4 v0 = tv[(size_t)s4.x*4 + l];
            float4 v1 = tv[(size_t)s4.y*4 + l];
            float4 v2 = tv[(size_t)s4.z*4 + l];
            float4 v3 = tv[(size_t)s4.w*4 + l];
            addrow8(acc, h2add4f(h2add4f(v0, v1), h2add4f(v2, v3)));
        }
        for (; e < e1; e++) addrow8(acc, tv[(size_t)esrc[e]*4 + l]);
        d = dis[n];
#pragma unroll
        for (int c = 0; c < 8; c++)
            acc[c] = elu1(fmaf(d, acc[c], bias[8*l + c]));
    }
    __syncthreads();
#pragma unroll
    for (int c = 0; c < 8; c++) sh[nib][8*l + c] = acc[c];
    __syncthreads();
    float o[8] = {0.f,0.f,0.f,0.f,0.f,0.f,0.f,0.f};
#pragma unroll
    for (int i = 0; i < HF; i++){
        float hvv = sh[nib][i];
        float4 w0 = *(const float4*)&sW[i*HF + 8*l];
        float4 w1 = *(const float4*)&sW[i*HF + 8*l + 4];
        o[0] = fmaf(hvv, w0.x, o[0]); o[1] = fmaf(hvv, w0.y, o[1]);
        o[2] = fmaf(hvv, w0.z, o[2]); o[3] = fmaf(hvv, w0.w, o[3]);
        o[4] = fmaf(hvv, w1.x, o[4]); o[5] = fmaf(hvv, w1.y, o[5]);
        o[6] = fmaf(hvv, w1.z, o[6]); o[7] = fmaf(hvv, w1.w, o[7]);
    }
    if (n < N){
        __half2 hh[4];
#pragma unroll
        for (int k = 0; k < 4; k++)
            hh[k] = __float22half2_rn(make_float2(o[2*k]*d, o[2*k+1]*d));
        ((float4*)tout)[(size_t)n*4 + l] = *(float4*)hh;
    }
}

// ------- final: gather layer3 + elu, output MLP + sigmoid col 0 -------------
__global__ __launch_bounds__(256)
void k_gather_out(const __half* __restrict__ tin, const int* __restrict__ esrc,
                  const int2* __restrict__ rowp2, const float* __restrict__ dis,
                  const float* __restrict__ bg3,
                  const float* __restrict__ wo1, const float* __restrict__ bo1,
                  const float* __restrict__ wo2, const float* __restrict__ bo2,
                  const float* __restrict__ wo3, const float* __restrict__ bo3,
                  float* __restrict__ out, int N){
    __shared__ float sW1[HF*HF], sW2[HF*HF], sW3[HF*4];
    __shared__ float sh[64][33], sh2[64][33];
    int tid = threadIdx.x;
    for (int i = tid; i < HF*HF; i += 256){ sW1[i] = wo1[i]; sW2[i] = wo2[i]; }
    if (tid < HF*4) sW3[tid] = wo3[tid];
    int nib = tid >> 2, l = tid & 3;
    int n = blockIdx.x*64 + nib;
    float acc[8] = {0.f,0.f,0.f,0.f,0.f,0.f,0.f,0.f};
    const float4* tv = (const float4*)tin;
    if (n < N){
        addrow8(acc, tv[(size_t)n*4 + l]);
        int2 r = rowp2[n];
        int e = r.x, e1 = r.y;
        while (e < e1 && (e & 3)){ addrow8(acc, tv[(size_t)esrc[e]*4 + l]); e++; }
        for (; e + 7 < e1; e += 8){
            int4 a4 = nt_load_i4(&esrc[e]);
            int4 b4 = nt_load_i4(&esrc[e+4]);
            float4 v0 = tv[(size_t)a4.x*4 + l];
            float4 v1 = tv[(size_t)a4.y*4 + l];
            float4 v2 = tv[(size_t)a4.z*4 + l];
            float4 v3 = tv[(size_t)a4.w*4 + l];
            float4 v4 = tv[(size_t)b4.x*4 + l];
            float4 v5 = tv[(size_t)b4.y*4 + l];
            float4 v6 = tv[(size_t)b4.z*4 + l];
            float4 v7 = tv[(size_t)b4.w*4 + l];
            addrow8(acc, h2add4f(h2add4f(v0, v1), h2add4f(v2, v3)));
            addrow8(acc, h2add4f(h2add4f(v4, v5), h2add4f(v6, v7)));
        }
        for (; e + 3 < e1; e += 4){
            int4 s4 = nt_load_i4(&esrc[e]);
            float4 v0 = tv[(size_t)s4.x*4 + l];
            float4 v1 = tv[(size_t)s4.y*4 + l];
            float4 v2 = tv[(size_t)s4.z*4 + l];
            float4 v3 = tv[(size_t)s4.w*4 + l];
            addrow8(acc, h2add4f(h2add4f(v0, v1), h2add4f(v2, v3)));
        }
        for (; e < e1; e++) addrow8(acc, tv[(size_t)esrc[e]*4 + l]);
        float d = dis[n];
#pragma unroll
        for (int c = 0; c < 8; c++)
            acc[c] = elu1(fmaf(d, acc[c], bg3[8*l + c]));
    }
    __syncthreads();
#pragma unroll
    for (int c = 0; c < 8; c++) sh[nib][8*l + c] = acc[c];
    __syncthreads();
    float o1[8];
#pragma unroll
    for (int c = 0; c < 8; c++) o1[c] = bo1[8*l + c];
#pragma unroll
    for (int i = 0; i < HF; i++){
        float hvv = sh[nib][i];
        float4 w0 = *(const float4*)&sW1[i*HF + 8*l];
        float4 w1 = *(const float4*)&sW1[i*HF + 8*l + 4];
        o1[0] = fmaf(hvv, w0.x, o1[0]); o1[1] = fmaf(hvv, w0.y, o1[1]);
        o1[2] = fmaf(hvv, w0.z, o1[2]); o1[3] = fmaf(hvv, w0.w, o1[3]);
        o1[4] = fmaf(hvv, w1.x, o1[4]); o1[5] = fmaf(hvv, w1.y, o1[5]);
        o1[6] = fmaf(hvv, w1.z, o1[6]); o1[7] = fmaf(hvv, w1.w, o1[7]);
    }
#pragma unroll
    for (int c = 0; c < 8; c++) sh2[nib][8*l + c] = leaky(o1[c]);
    __syncthreads();
    float o2[8];
#pragma unroll
    for (int c = 0; c < 8; c++) o2[c] = bo2[8*l + c];
#pragma unroll
    for (int i = 0; i < HF; i++){
        float hvv = sh2[nib][i];
        float4 w0 = *(const float4*)&sW2[i*HF + 8*l];
        float4 w1 = *(const float4*)&sW2[i*HF + 8*l + 4];
        o2[0] = fmaf(hvv, w0.x, o2[0]); o2[1] = fmaf(hvv, w0.y, o2[1]);
        o2[2] = fmaf(hvv, w0.z, o2[2]); o2[3] = fmaf(hvv, w0.w, o2[3]);
        o2[4] = fmaf(hvv, w1.x, o2[4]); o2[5] = fmaf(hvv, w1.y, o2[5]);
        o2[6] = fmaf(hvv, w1.z, o2[6]); o2[7] = fmaf(hvv, w1.w, o2[7]);
    }
#pragma unroll
    for (int c = 0; c < 8; c++) sh[nib][8*l + c] = leaky(o2[c]);
    __syncthreads();
    if (n < N){
        float v = bo3[l];
#pragma unroll
        for (int i = 0; i < HF; i++) v = fmaf(sh[nib][i], sW3[i*4 + l], v);
        if (l == 0) v = sigmoidf(v);
        out[(size_t)n*4 + l] = v;
    }
}

extern "C" void kernel_launch(void* const* d_in, const int* in_sizes, int n_in,
                              void* d_out, int out_size, void* d_ws, size_t ws_size,
                              hipStream_t stream) {
    const float* x     = (const float*)d_in[0];
    const float* w_in1 = (const float*)d_in[1];
    const float* b_in1 = (const float*)d_in[2];
    const float* w_in2 = (const float*)d_in[3];
    const float* b_in2 = (const float*)d_in[4];
    const float* gamma = (const float*)d_in[5];
    const float* beta  = (const float*)d_in[6];
    const float* wg1   = (const float*)d_in[7];
    const float* bg1   = (const float*)d_in[8];
    const float* wg2   = (const float*)d_in[9];
    const float* bg2   = (const float*)d_in[10];
    const float* wg3   = (const float*)d_in[11];
    const float* bg3   = (const float*)d_in[12];
    const float* wo1   = (const float*)d_in[13];
    const float* bo1   = (const float*)d_in[14];
    const float* wo2   = (const float*)d_in[15];
    const float* bo2   = (const float*)d_in[16];
    const float* wo3   = (const float*)d_in[17];
    const float* bo3   = (const float*)d_in[18];
    const int*   ei    = (const int*)d_in[19];

    int N = in_sizes[0] / 3;
    int E = in_sizes[19] / 2;
    int B = (N + BSZ - 1) >> BSH;          // buckets (782; lcnt arrays hold 1024)

    char* w = (char*)d_ws;
    size_t o = 0;
    auto alloc = [&](size_t bytes){ size_t r = o; o = (o + bytes + 255) & ~(size_t)255; return r; };
    // ---- zeroed region ----
    float* stats = (float*)(w + alloc(2*HF*sizeof(float)));
    int*   gfill = (int*)  (w + alloc((size_t)B*8*4));
    size_t zero_bytes = o;
    // ---- rest ----
    int2*  rowp2 = (int2*) (w + alloc((size_t)N*8));
    float* dis   = (float*)(w + alloc((size_t)N*4));
    int*   ep    = (int*)  (w + alloc((size_t)B*CAP*4));
    __half* bufH = (__half*)(w + alloc((size_t)N*HF*2));
    __half* tA   = (__half*)(w + alloc((size_t)N*HF*2));
    __half* tB   = (__half*)(w + alloc((size_t)N*HF*2));

    hipMemsetAsync(d_ws, 0, zero_bytes, stream);

    const int* src = ei;
    const int* dst = ei + E;
    int NB1 = (N + 255) / 256;
    int NC  = (E + CH - 1) / CH;
    int GB  = (N + 63) / 64;

    k_mlp_bin<<<NB1 + NC, 256, 0, stream>>>(x, w_in1, b_in1, w_in2, b_in2, bufH, stats,
                                            src, dst, gfill, ep, N, E, B, NB1);
    k_bucketD<<<B, 256, 0, stream>>>(ep, gfill, rowp2, dis, N, B);

    k_bn_t1   <<<GB, 256, 0, stream>>>(bufH, stats, gamma, beta, wg1, dis, tA, N);
    k_gather_t<<<GB, 256, 0, stream>>>(tA, ep, rowp2, dis, bg1, wg2, tB, N);
    k_gather_t<<<GB, 256, 0, stream>>>(tB, ep, rowp2, dis, bg2, wg3, tA, N);
    k_gather_out<<<GB, 256, 0, stream>>>(tA, ep, rowp2, dis, bg3,
                                         wo1, bo1, wo2, bo2, wo3, bo3, (float*)d_out, N);
}